// Round 3
// baseline (2115.679 us; speedup 1.0000x reference)
//
#include <hip/hip_runtime.h>
#include <hip/hip_bf16.h>

#define N 4096
#define D 512
#define RPB 8   // rows per block in sinkhorn kernel

typedef unsigned short u16;
typedef __attribute__((ext_vector_type(8))) short short8;
typedef __attribute__((ext_vector_type(8))) unsigned short ushort8;
typedef __attribute__((ext_vector_type(4))) float fvec4;

static __device__ __forceinline__ float bf2f(unsigned short u) {
    union { unsigned int i; float f; } c;
    c.i = ((unsigned int)u) << 16;
    return c.f;
}

static __device__ __forceinline__ unsigned short f2bf(float x) {
    __hip_bfloat16 h = __float2bfloat16(x);  // RNE
    unsigned short u;
    __builtin_memcpy(&u, &h, 2);
    return u;
}

static __device__ __forceinline__ void gld_lds16(const u16* gp, u16* lp) {
    __builtin_amdgcn_global_load_lds(
        (__attribute__((address_space(1))) void*)(u16*)gp,
        (__attribute__((address_space(3))) void*)lp, 16, 0, 0);
}

// ---------------- fp32 -> bf16 convert (8 elems/thread) ----------------
__global__ __launch_bounds__(256) void f32_to_bf16_k(const float* __restrict__ in,
                                                     u16* __restrict__ out) {
    int idx = blockIdx.x * 256 + threadIdx.x;
    fvec4 a = *((const fvec4*)in + idx * 2);
    fvec4 b = *((const fvec4*)in + idx * 2 + 1);
    ushort8 o;
#pragma unroll
    for (int e = 0; e < 4; ++e) { o[e] = f2bf(a[e]); o[4 + e] = f2bf(b[e]); }
    *((ushort8*)out + idx) = o;
}

// ---------------- row squared-norms: one wave per row ----------------
__global__ __launch_bounds__(256) void row_norms_k(const float* __restrict__ X,
                                                   float* __restrict__ out) {
    int wave = threadIdx.x >> 6;
    int lane = threadIdx.x & 63;
    int row  = blockIdx.x * 4 + wave;
    const float* xr = X + (size_t)row * D;
    float s = 0.f;
#pragma unroll
    for (int k = 0; k < D / 64; ++k) {
        float v = xr[lane + 64 * k];
        s += v * v;
    }
#pragma unroll
    for (int off = 32; off >= 1; off >>= 1) s += __shfl_down(s, off);
    if (lane == 0) out[row] = s;
}

// ---------------- cost matrix via bf16 MFMA (m97 pattern) ----------------
__global__ __launch_bounds__(256) void gemm_cost_bf16_k(const u16* __restrict__ A,
                                                        const u16* __restrict__ B,
                                                        const float* __restrict__ x2,
                                                        const float* __restrict__ y2,
                                                        u16* __restrict__ M) {
    __shared__ u16 As[128 * 32];  // [row][k] row-major, unpadded (global_load_lds)
    __shared__ u16 Bs[128 * 32];
    int tid = threadIdx.x;
    int wave = tid >> 6, lane = tid & 63;
    int i0 = blockIdx.y * 128, j0 = blockIdx.x * 128;
    int wr = (wave >> 1) * 64, wc = (wave & 1) * 64;

    fvec4 acc[4][4] = {};

    int srow = wave * 16 + (lane >> 2);
    int skk  = (lane & 3) * 8;
    const u16* ga0 = A + (size_t)(i0 + srow) * D + skk;
    const u16* ga1 = A + (size_t)(i0 + 64 + srow) * D + skk;
    const u16* gb0 = B + (size_t)(j0 + srow) * D + skk;
    const u16* gb1 = B + (size_t)(j0 + 64 + srow) * D + skk;
    u16* la0 = &As[(wave * 16) * 32];
    u16* la1 = &As[(64 + wave * 16) * 32];
    u16* lb0 = &Bs[(wave * 16) * 32];
    u16* lb1 = &Bs[(64 + wave * 16) * 32];

    int fr = lane & 15, q = lane >> 4;

    for (int k0 = 0; k0 < D; k0 += 32) {
        __syncthreads();
        gld_lds16(ga0 + k0, la0);
        gld_lds16(ga1 + k0, la1);
        gld_lds16(gb0 + k0, lb0);
        gld_lds16(gb1 + k0, lb1);
        __syncthreads();
        short8 af[4], bf[4];
#pragma unroll
        for (int t = 0; t < 4; ++t) {
            af[t] = *(const short8*)&As[(wr + t * 16 + fr) * 32 + q * 8];
            bf[t] = *(const short8*)&Bs[(wc + t * 16 + fr) * 32 + q * 8];
        }
#pragma unroll
        for (int ri = 0; ri < 4; ++ri)
#pragma unroll
            for (int ci = 0; ci < 4; ++ci)
                acc[ri][ci] = __builtin_amdgcn_mfma_f32_16x16x32_bf16(af[ri], bf[ci],
                                                                      acc[ri][ci], 0, 0, 0);
    }

#pragma unroll
    for (int ri = 0; ri < 4; ++ri) {
#pragma unroll
        for (int ci = 0; ci < 4; ++ci) {
            int j = j0 + wc + ci * 16 + fr;
            float yj = y2[j];
#pragma unroll
            for (int r = 0; r < 4; ++r) {
                int i = i0 + wr + ri * 16 + q * 4 + r;
                float val = fmaxf(x2[i] + yj - 2.0f * acc[ri][ci][r], 0.0f);
                M[(size_t)i * N + j] = f2bf(val);
            }
        }
    }
}

// ---------------- bf16 LDS-tiled transpose ----------------
__global__ __launch_bounds__(256) void transpose_bf16_k(const u16* __restrict__ in,
                                                        u16* __restrict__ out) {
    __shared__ u16 tile[64][66];
    int bx = blockIdx.x * 64, by = blockIdx.y * 64;
    int tx = threadIdx.x & 63, ty = threadIdx.x >> 6;
#pragma unroll
    for (int r = 0; r < 64; r += 4)
        tile[r + ty][tx] = in[(size_t)(by + r + ty) * N + bx + tx];
    __syncthreads();
#pragma unroll
    for (int r = 0; r < 64; r += 4)
        out[(size_t)(bx + r + ty) * N + by + tx] = tile[tx][r + ty];
}

// ---------------- Sinkhorn half-step, 8 rows per block ----------------
// vout[row] = logw - LSE_j( vin[j] - Mr[row][j] )
// Thread t owns columns {t*8..t*8+7} and {2048+t*8..+7} for all 8 rows.
// g in VGPRs (loaded once), 8 rows of packed bf16 M in VGPRs, 2 barriers total.
__global__ __launch_bounds__(256) void sinkhorn_multi_k(const u16* __restrict__ Mr,
                                                        const float* __restrict__ vin,
                                                        float* __restrict__ vout,
                                                        float logw) {
    int t = threadIdx.x;
    int row0 = blockIdx.x * RPB;
    int wave = t >> 6, lane = t & 63;
    const u16* base = Mr + (size_t)row0 * N + t * 8;

    fvec4 gr[4];
    gr[0] = *(const fvec4*)(vin + t * 8);
    gr[1] = *(const fvec4*)(vin + t * 8 + 4);
    gr[2] = *(const fvec4*)(vin + 2048 + t * 8);
    gr[3] = *(const fvec4*)(vin + 2048 + t * 8 + 4);

    ushort8 mrow[RPB][2];
#pragma unroll
    for (int r = 0; r < RPB; ++r) {
        mrow[r][0] = *(const ushort8*)(base + (size_t)r * N);
        mrow[r][1] = *(const ushort8*)(base + (size_t)r * N + 2048);
    }

    // phase 1: per-row max
    float mx[RPB];
#pragma unroll
    for (int r = 0; r < RPB; ++r) {
        float m = -3.4e38f;
#pragma unroll
        for (int h = 0; h < 2; ++h)
#pragma unroll
            for (int e = 0; e < 8; ++e) {
                float tv = gr[h * 2 + (e >> 2)][e & 3] - bf2f(mrow[r][h][e]);
                m = fmaxf(m, tv);
            }
        mx[r] = m;
    }
#pragma unroll
    for (int off = 32; off >= 1; off >>= 1)
#pragma unroll
        for (int r = 0; r < RPB; ++r)
            mx[r] = fmaxf(mx[r], __shfl_down(mx[r], off));

    __shared__ float smax[RPB][4];
    __shared__ float ssum[RPB][4];
    if (lane == 0)
#pragma unroll
        for (int r = 0; r < RPB; ++r) smax[r][wave] = mx[r];
    __syncthreads();

    float bm[RPB];
#pragma unroll
    for (int r = 0; r < RPB; ++r)
        bm[r] = fmaxf(fmaxf(smax[r][0], smax[r][1]), fmaxf(smax[r][2], smax[r][3]));

    // phase 2: sum of exp relative to block max
    float sv[RPB];
#pragma unroll
    for (int r = 0; r < RPB; ++r) {
        float s = 0.f;
#pragma unroll
        for (int h = 0; h < 2; ++h)
#pragma unroll
            for (int e = 0; e < 8; ++e) {
                float tv = gr[h * 2 + (e >> 2)][e & 3] - bf2f(mrow[r][h][e]);
                s += __expf(tv - bm[r]);
            }
        sv[r] = s;
    }
#pragma unroll
    for (int off = 32; off >= 1; off >>= 1)
#pragma unroll
        for (int r = 0; r < RPB; ++r) sv[r] += __shfl_down(sv[r], off);
    if (lane == 0)
#pragma unroll
        for (int r = 0; r < RPB; ++r) ssum[r][wave] = sv[r];
    __syncthreads();

    if (t < RPB) {
        float S = ssum[t][0] + ssum[t][1] + ssum[t][2] + ssum[t][3];
        float bmt = fmaxf(fmaxf(smax[t][0], smax[t][1]),
                          fmaxf(smax[t][2], smax[t][3]));
        vout[row0 + t] = logw - (bmt + __logf(S));
    }
}

// ---------------- final objective, spread-slot atomics ----------------
// value = sum_ij p*(f_i + g_j - la - lb - 1) + 1,  p = exp(f_i + g_j - M_ij)
__global__ __launch_bounds__(256) void ot_value_bf16_k(const u16* __restrict__ M,
                                                       const float* __restrict__ f,
                                                       const float* __restrict__ g,
                                                       float* __restrict__ slots,
                                                       float lab) {
    int row = blockIdx.x;
    const u16* Mrow = M + (size_t)row * N;
    float fi = f[row];
    int t = threadIdx.x;
    ushort8 m0 = *(const ushort8*)(Mrow + t * 8);
    ushort8 m1 = *(const ushort8*)(Mrow + 2048 + t * 8);
    fvec4 ga0 = *(const fvec4*)(g + t * 8);
    fvec4 ga1 = *(const fvec4*)(g + t * 8 + 4);
    fvec4 gb0 = *(const fvec4*)(g + 2048 + t * 8);
    fvec4 gb1 = *(const fvec4*)(g + 2048 + t * 8 + 4);
    float local = 0.f;
#pragma unroll
    for (int e = 0; e < 4; ++e) {
        float mv, lp;
        mv = bf2f(m0[e]);     lp = fi + ga0[e] - mv; local += __expf(lp) * (mv + lp - lab - 1.0f);
        mv = bf2f(m0[4 + e]); lp = fi + ga1[e] - mv; local += __expf(lp) * (mv + lp - lab - 1.0f);
        mv = bf2f(m1[e]);     lp = fi + gb0[e] - mv; local += __expf(lp) * (mv + lp - lab - 1.0f);
        mv = bf2f(m1[4 + e]); lp = fi + gb1[e] - mv; local += __expf(lp) * (mv + lp - lab - 1.0f);
    }
#pragma unroll
    for (int off = 32; off >= 1; off >>= 1) local += __shfl_down(local, off);
    __shared__ float ps[4];
    int wave = t >> 6, lane = t & 63;
    if (lane == 0) ps[wave] = local;
    __syncthreads();
    if (t == 0) {
        float sum = ps[0] + ps[1] + ps[2] + ps[3];
        atomicAdd(&slots[row & 63], sum);
    }
}

__global__ __launch_bounds__(64) void final_sum_k(const float* __restrict__ slots,
                                                  float* __restrict__ out) {
    int t = threadIdx.x;
    float s = slots[t];
#pragma unroll
    for (int off = 32; off >= 1; off >>= 1) s += __shfl_down(s, off);
    if (t == 0) out[0] = s + 1.0f;
}

extern "C" void kernel_launch(void* const* d_in, const int* in_sizes, int n_in,
                              void* d_out, int out_size, void* d_ws, size_t ws_size,
                              hipStream_t stream) {
    const float* src = (const float*)d_in[0];
    const float* tgt = (const float*)d_in[1];
    float* out = (float*)d_out;

    // workspace: Mb (32MB) | MTb (32MB) | Xb (4MB) | Yb (4MB) | x2 | y2 | f | g | slots
    u16* Mb  = (u16*)d_ws;
    u16* MTb = Mb + (size_t)N * N;
    u16* Xb  = MTb + (size_t)N * N;
    u16* Yb  = Xb + (size_t)N * D;
    float* x2 = (float*)(Yb + (size_t)N * D);
    float* y2 = x2 + N;
    float* f  = y2 + N;
    float* g  = f + N;
    float* slots = g + N;

    const float la = -8.317766166719343f;  // -log(4096)
    const float lb = la;

    hipMemsetAsync(f, 0, (2 * N + 64) * sizeof(float), stream);  // f, g, slots

    f32_to_bf16_k<<<N * D / (256 * 8), 256, 0, stream>>>(src, Xb);
    f32_to_bf16_k<<<N * D / (256 * 8), 256, 0, stream>>>(tgt, Yb);
    row_norms_k<<<N / 4, 256, 0, stream>>>(src, x2);
    row_norms_k<<<N / 4, 256, 0, stream>>>(tgt, y2);
    gemm_cost_bf16_k<<<dim3(N / 128, N / 128), 256, 0, stream>>>(Xb, Yb, x2, y2, Mb);
    transpose_bf16_k<<<dim3(N / 64, N / 64), 256, 0, stream>>>(Mb, MTb);

    for (int it = 0; it < 100; ++it) {
        sinkhorn_multi_k<<<N / RPB, 256, 0, stream>>>(Mb,  g, f, la);
        sinkhorn_multi_k<<<N / RPB, 256, 0, stream>>>(MTb, f, g, lb);
    }

    ot_value_bf16_k<<<N, 256, 0, stream>>>(Mb, f, g, slots, la + lb);
    final_sum_k<<<1, 64, 0, stream>>>(slots, out);
}